// Round 1
// baseline (218.529 us; speedup 1.0000x reference)
//
#include <hip/hip_runtime.h>

#define IN_F 1024
#define OUT_F 1024
#define NT 1024
#define RANK 32
#define M_TOT 8192   // 4*2048 query rows
#define N2T 2048     // 2*NT combined tokens

typedef __attribute__((ext_vector_type(8))) short short8;
typedef __attribute__((ext_vector_type(4))) float f32x4;
typedef __attribute__((ext_vector_type(8))) unsigned short ushort8;

__device__ __forceinline__ float geluf(float x) {
  return 0.5f * x * (1.0f + erff(x * 0.7071067811865476f));
}
__device__ __forceinline__ unsigned short f2bf(float f) {
  unsigned x = __float_as_uint(f);
  return (unsigned short)((x + 0x7fffu + ((x >> 16) & 1u)) >> 16);
}
__device__ __forceinline__ float bf2f(unsigned short u) {
  return __uint_as_float(((unsigned)u) << 16);
}

// ---- tiny prep kernels -----------------------------------------------------

// tmpK = key_tokens @ key_down, tmpV = value_tokens @ value_down  ([1024][32] f32)
__global__ void down_proj_kernel(const float* __restrict__ kt, const float* __restrict__ kd,
                                 const float* __restrict__ vt, const float* __restrict__ vd,
                                 float* __restrict__ tmpK, float* __restrict__ tmpV) {
  int idx = blockIdx.x * blockDim.x + threadIdx.x;  // 65536 threads
  int c = idx & 31;
  int row = (idx >> 5) & (NT - 1);
  int mat = idx >> 15;
  const float* T = mat ? vt : kt;
  const float* D = mat ? vd : kd;
  float s = 0.f;
  for (int k = 0; k < IN_F; ++k)
    s += T[row * IN_F + k] * D[k * RANK + c];
  (mat ? tmpV : tmpK)[row * RANK + c] = s;
}

// Kb[t][d] (bf16, [2048][1024]): first half = key_tokens, second = gelu(tmpK @ key_up)
__global__ void kfill_kernel(const float* __restrict__ key_tokens, const float* __restrict__ key_up,
                             const float* __restrict__ tmpK, unsigned short* __restrict__ Kb) {
  int idx = blockIdx.x * blockDim.x + threadIdx.x;  // 2048*1024
  int d = idx & (IN_F - 1);
  int t = idx >> 10;
  float v;
  if (t < NT) {
    v = key_tokens[idx];
  } else {
    int tt = t - NT;
    float s = 0.f;
#pragma unroll
    for (int r = 0; r < RANK; ++r) s += tmpK[tt * RANK + r] * key_up[r * IN_F + d];
    v = geluf(s);
  }
  Kb[idx] = f2bf(v);
}

// VbT[e][t] (bf16, [1024][2048]): transposed combined values
__global__ void vfill_kernel(const float* __restrict__ value_tokens, const float* __restrict__ value_up,
                             const float* __restrict__ tmpV, unsigned short* __restrict__ VbT) {
  int idx = blockIdx.x * blockDim.x + threadIdx.x;  // 1024*2048
  int t = idx & (N2T - 1);
  int e = idx >> 11;
  float v;
  if (t < NT) {
    v = value_tokens[t * OUT_F + e];
  } else {
    int tt = t - NT;
    float s = 0.f;
#pragma unroll
    for (int r = 0; r < RANK; ++r) s += tmpV[tt * RANK + r] * value_up[r * OUT_F + e];
    v = geluf(s);
  }
  VbT[idx] = f2bf(v);
}

// xb = bf16(x), [8192][1024]
__global__ void xcast_kernel(const float* __restrict__ x, unsigned short* __restrict__ xb) {
  int base = (blockIdx.x * blockDim.x + threadIdx.x) * 8;
  f32x4 a = *(const f32x4*)(x + base);
  f32x4 b = *(const f32x4*)(x + base + 4);
  ushort8 o;
  o[0] = f2bf(a[0]); o[1] = f2bf(a[1]); o[2] = f2bf(a[2]); o[3] = f2bf(a[3]);
  o[4] = f2bf(b[0]); o[5] = f2bf(b[1]); o[6] = f2bf(b[2]); o[7] = f2bf(b[3]);
  *(ushort8*)(xb + base) = o;
}

// W = gelu(S * sqrt(2048/rowsq)) in place (bf16)
__global__ void gelu_kernel(unsigned short* __restrict__ S, const float* __restrict__ rowsq) {
  int base = (blockIdx.x * blockDim.x + threadIdx.x) * 8;
  int row = base >> 11;  // 2048 per row
  float scale = sqrtf(2048.0f / rowsq[row]);
  ushort8 v = *(const ushort8*)(S + base);
  ushort8 o;
#pragma unroll
  for (int i = 0; i < 8; ++i) o[i] = f2bf(geluf(bf2f(v[i]) * scale));
  *(ushort8*)(S + base) = o;
}

// ---- main GEMM: C[M,N] = A[M,K] * B[N,K]^T, bf16 inputs --------------------
// m97 structure: 128x128 tile, BK=64, 4 waves (2x2 of 64x64), global_load_lds
// width 16, XOR swizzle (byte ^= (row&7)<<4) applied to BOTH the pre-swizzled
// global source and the ds_read address (rule #21).
template <int DO_SIM>
__global__ __launch_bounds__(256) void gemm_bt_kernel(
    const unsigned short* __restrict__ A, const unsigned short* __restrict__ Bm,
    void* __restrict__ Cout, float* __restrict__ rowsq, int N, int K) {
  __shared__ unsigned short lds[2 * 128 * 64];  // 16KB A + 16KB B
  const int tid = threadIdx.x;
  const int l = tid & 63;
  const int w = tid >> 6;
  const int rowBase = blockIdx.y * 128;
  const int colBase = blockIdx.x * 128;
  const int wr = w >> 1, wc = w & 1;

  // staging source coords: lane l writes LDS phys (row=+l/8, 16B slot l%8);
  // logical col chunk = phys chunk ^ (row&7)
  const int srow = l >> 3;                           // 0..7 (== row&7, rows 8-aligned)
  const int scole = (((l & 7) * 16) ^ (srow << 4)) >> 1;  // source col in elems

  f32x4 acc[4][4];
#pragma unroll
  for (int m = 0; m < 4; ++m)
#pragma unroll
    for (int n = 0; n < 4; ++n) acc[m][n] = (f32x4){0.f, 0.f, 0.f, 0.f};

  const int arow0 = wr * 64 + (l & 15);
  const int brow0 = wc * 64 + (l & 15);
  const int kb0 = (l >> 4) * 16;  // byte offset of this lane's K-chunk

  unsigned short* ldsA = lds;
  unsigned short* ldsB = lds + 128 * 64;

  const int nkt = K >> 6;
  for (int kt = 0; kt < nkt; ++kt) {
    const int k0 = kt * 64;
#pragma unroll
    for (int j = 0; j < 4; ++j) {
      int r = w * 32 + j * 8 + srow;
      const unsigned short* g = A + (size_t)(rowBase + r) * K + k0 + scole;
      __builtin_amdgcn_global_load_lds(
          (const __attribute__((address_space(1))) void*)g,
          (__attribute__((address_space(3))) void*)(ldsA + (w * 4 + j) * 512),
          16, 0, 0);
    }
#pragma unroll
    for (int j = 0; j < 4; ++j) {
      int r = w * 32 + j * 8 + srow;
      const unsigned short* g = Bm + (size_t)(colBase + r) * K + k0 + scole;
      __builtin_amdgcn_global_load_lds(
          (const __attribute__((address_space(1))) void*)g,
          (__attribute__((address_space(3))) void*)(ldsB + (w * 4 + j) * 512),
          16, 0, 0);
    }
    __syncthreads();
#pragma unroll
    for (int kk = 0; kk < 2; ++kk) {
      short8 af[4], bfr[4];
      const int kbyte = kk * 64 + kb0;
#pragma unroll
      for (int m = 0; m < 4; ++m) {
        int rr = arow0 + m * 16;
        af[m] = *(const short8*)((const char*)ldsA + rr * 128 + (kbyte ^ ((rr & 7) << 4)));
      }
#pragma unroll
      for (int n = 0; n < 4; ++n) {
        int rr = brow0 + n * 16;
        bfr[n] = *(const short8*)((const char*)ldsB + rr * 128 + (kbyte ^ ((rr & 7) << 4)));
      }
#pragma unroll
      for (int m = 0; m < 4; ++m)
#pragma unroll
        for (int n = 0; n < 4; ++n)
          acc[m][n] = __builtin_amdgcn_mfma_f32_16x16x32_bf16(af[m], bfr[n], acc[m][n], 0, 0, 0);
    }
    __syncthreads();
  }

  // epilogue: C/D layout col=lane&15, row=(lane>>4)*4+reg (m89/m91)
  const int cq = l >> 4;
  const int cc = l & 15;
  if (DO_SIM) {
    unsigned short* Sb = (unsigned short*)Cout;
#pragma unroll
    for (int m = 0; m < 4; ++m) {
#pragma unroll
      for (int j = 0; j < 4; ++j) {
        int gr = rowBase + wr * 64 + m * 16 + cq * 4 + j;
        float ss = 0.f;
#pragma unroll
        for (int n = 0; n < 4; ++n) {
          float v = acc[m][n][j];
          ss += v * v;
          int gc = colBase + wc * 64 + n * 16 + cc;
          Sb[(size_t)gr * N + gc] = f2bf(v);
        }
        ss += __shfl_xor(ss, 1, 64);
        ss += __shfl_xor(ss, 2, 64);
        ss += __shfl_xor(ss, 4, 64);
        ss += __shfl_xor(ss, 8, 64);
        if (cc == 0) atomicAdd(&rowsq[gr], ss);
      }
    }
  } else {
    float* Co = (float*)Cout;
#pragma unroll
    for (int m = 0; m < 4; ++m) {
#pragma unroll
      for (int j = 0; j < 4; ++j) {
        int gr = rowBase + wr * 64 + m * 16 + cq * 4 + j;
#pragma unroll
        for (int n = 0; n < 4; ++n) {
          int gc = colBase + wc * 64 + n * 16 + cc;
          Co[(size_t)gr * N + gc] = acc[m][n][j];
        }
      }
    }
  }
}

// ---- launch ----------------------------------------------------------------

extern "C" void kernel_launch(void* const* d_in, const int* in_sizes, int n_in,
                              void* d_out, int out_size, void* d_ws, size_t ws_size,
                              hipStream_t stream) {
  (void)in_sizes; (void)n_in; (void)out_size; (void)ws_size;
  const float* x            = (const float*)d_in[0];
  const float* key_tokens   = (const float*)d_in[1];
  const float* value_tokens = (const float*)d_in[2];
  const float* key_down     = (const float*)d_in[3];
  const float* key_up       = (const float*)d_in[4];
  const float* value_down   = (const float*)d_in[5];
  const float* value_up     = (const float*)d_in[6];

  char* ws = (char*)d_ws;
  unsigned short* xb  = (unsigned short*)(ws);              // 16 MB  [8192][1024]
  unsigned short* Kb  = (unsigned short*)(ws + 16777216);   // 4 MB   [2048][1024]
  unsigned short* VbT = (unsigned short*)(ws + 20971520);   // 4 MB   [1024][2048]
  unsigned short* S   = (unsigned short*)(ws + 25165824);   // 32 MB  [8192][2048]
  float* tmpK  = (float*)(ws + 58720256);                   // 128 KB
  float* tmpV  = (float*)(ws + 58851328);                   // 128 KB
  float* rowsq = (float*)(ws + 58982400);                   // 32 KB

  hipMemsetAsync(rowsq, 0, M_TOT * sizeof(float), stream);
  down_proj_kernel<<<256, 256, 0, stream>>>(key_tokens, key_down, value_tokens, value_down, tmpK, tmpV);
  kfill_kernel<<<(N2T * IN_F) / 256, 256, 0, stream>>>(key_tokens, key_up, tmpK, Kb);
  vfill_kernel<<<(OUT_F * N2T) / 256, 256, 0, stream>>>(value_tokens, value_up, tmpV, VbT);
  xcast_kernel<<<(M_TOT * IN_F) / (256 * 8), 256, 0, stream>>>(x, xb);
  gemm_bt_kernel<1><<<dim3(N2T / 128, M_TOT / 128), 256, 0, stream>>>(xb, Kb, (void*)S, rowsq, N2T, IN_F);
  gelu_kernel<<<(M_TOT * N2T) / (256 * 8), 256, 0, stream>>>(S, rowsq);
  gemm_bt_kernel<0><<<dim3(OUT_F / 128, M_TOT / 128), 256, 0, stream>>>(S, VbT, d_out, nullptr, OUT_F, N2T);
}

// Round 2
// 181.802 us; speedup vs baseline: 1.2020x; 1.2020x over previous
//
#include <hip/hip_runtime.h>

#define IN_F 1024
#define OUT_F 1024
#define NT 1024
#define RANK 32
#define M_TOT 8192   // 4*2048 query rows
#define N2T 2048     // 2*NT combined tokens

typedef __attribute__((ext_vector_type(8))) short short8;
typedef __attribute__((ext_vector_type(4))) float f32x4;
typedef __attribute__((ext_vector_type(8))) unsigned short ushort8;

__device__ __forceinline__ float geluf(float x) {
  return 0.5f * x * (1.0f + erff(x * 0.7071067811865476f));
}
__device__ __forceinline__ unsigned short f2bf(float f) {
  unsigned x = __float_as_uint(f);
  return (unsigned short)((x + 0x7fffu + ((x >> 16) & 1u)) >> 16);
}
__device__ __forceinline__ float bf2f(unsigned short u) {
  return __uint_as_float(((unsigned)u) << 16);
}

// ---- tiny prep kernels -----------------------------------------------------

__global__ void down_proj_kernel(const float* __restrict__ kt, const float* __restrict__ kd,
                                 const float* __restrict__ vt, const float* __restrict__ vd,
                                 float* __restrict__ tmpK, float* __restrict__ tmpV) {
  int idx = blockIdx.x * blockDim.x + threadIdx.x;  // 65536 threads
  int c = idx & 31;
  int row = (idx >> 5) & (NT - 1);
  int mat = idx >> 15;
  const float* T = mat ? vt : kt;
  const float* D = mat ? vd : kd;
  float s = 0.f;
  for (int k = 0; k < IN_F; ++k)
    s += T[row * IN_F + k] * D[k * RANK + c];
  (mat ? tmpV : tmpK)[row * RANK + c] = s;
}

__global__ void kfill_kernel(const float* __restrict__ key_tokens, const float* __restrict__ key_up,
                             const float* __restrict__ tmpK, unsigned short* __restrict__ Kb) {
  int idx = blockIdx.x * blockDim.x + threadIdx.x;  // 2048*1024
  int d = idx & (IN_F - 1);
  int t = idx >> 10;
  float v;
  if (t < NT) {
    v = key_tokens[idx];
  } else {
    int tt = t - NT;
    float s = 0.f;
#pragma unroll
    for (int r = 0; r < RANK; ++r) s += tmpK[tt * RANK + r] * key_up[r * IN_F + d];
    v = geluf(s);
  }
  Kb[idx] = f2bf(v);
}

// VbT[e][t] via LDS transpose: coalesced reads of value_tokens AND coalesced writes
__global__ void vfill_kernel(const float* __restrict__ vt, const float* __restrict__ vu,
                             const float* __restrict__ tmpV, unsigned short* __restrict__ VbT) {
  __shared__ float tile[64][65];
  int tid = threadIdx.x;
  int bt = blockIdx.x & 31;   // t-tile (2048/64)
  int be = blockIdx.x >> 5;   // e-tile (1024/64)
  int t0 = bt * 64, e0 = be * 64;
#pragma unroll 1
  for (int it = 0; it < 16; ++it) {
    int tt = it * 4 + (tid >> 6);
    int ee = tid & 63;
    int t = t0 + tt, e = e0 + ee;
    float v;
    if (t < NT) {
      v = vt[(size_t)t * OUT_F + e];
    } else {
      int q = t - NT;
      float s = 0.f;
#pragma unroll
      for (int r = 0; r < RANK; ++r) s += tmpV[q * RANK + r] * vu[r * OUT_F + e];
      v = geluf(s);
    }
    tile[tt][ee] = v;
  }
  __syncthreads();
#pragma unroll 1
  for (int it = 0; it < 16; ++it) {
    int ee = it * 4 + (tid >> 6);
    int tt = tid & 63;
    VbT[(size_t)(e0 + ee) * N2T + t0 + tt] = f2bf(tile[tt][ee]);
  }
}

__global__ void xcast_kernel(const float* __restrict__ x, unsigned short* __restrict__ xb) {
  int base = (blockIdx.x * blockDim.x + threadIdx.x) * 8;
  f32x4 a = *(const f32x4*)(x + base);
  f32x4 b = *(const f32x4*)(x + base + 4);
  ushort8 o;
  o[0] = f2bf(a[0]); o[1] = f2bf(a[1]); o[2] = f2bf(a[2]); o[3] = f2bf(a[3]);
  o[4] = f2bf(b[0]); o[5] = f2bf(b[1]); o[6] = f2bf(b[2]); o[7] = f2bf(b[3]);
  *(ushort8*)(xb + base) = o;
}

__global__ void gelu_kernel(unsigned short* __restrict__ S, const float* __restrict__ rowsq) {
  int base = (blockIdx.x * blockDim.x + threadIdx.x) * 8;
  int row = base >> 11;  // 2048 per row
  float scale = sqrtf(2048.0f / rowsq[row]);
  ushort8 v = *(const ushort8*)(S + base);
  ushort8 o;
#pragma unroll
  for (int i = 0; i < 8; ++i) o[i] = f2bf(geluf(bf2f(v[i]) * scale));
  *(ushort8*)(S + base) = o;
}

// ---- 8-phase GEMM: C[M,N] = A[M,K]*B[N,K]^T, bf16, BM=256, BK=64, 8 waves --
// Interleaved wave tiling: row = m*32 + wr*16, col = n*64 + wc*16 so phase
// quadrant (mh,nh) reads exactly A-half mh / B-half nh for every wave.
// LDS-region deaths: A0,B0 @p0; B1 @p1; A1 @p2.
// Stage slots: p0 -> (t+1).A1 [other buf], p1 -> (t+2).A0, p2 -> (t+2).B0,
// p3 -> (t+2).B1 [all into just-dead regions of current buf].
// Boundary vmcnt(2+2*LB) leaves exactly the 3 newest (t+2) units in flight.

#define BARR asm volatile("s_barrier" ::: "memory")
#define VMC6 asm volatile("s_waitcnt vmcnt(6)" ::: "memory")
#define VMC4 asm volatile("s_waitcnt vmcnt(4)" ::: "memory")

template <int BN, int DO_SIM>
__global__ __launch_bounds__(512, 2) void gemm8p_kernel(
    const unsigned short* __restrict__ A, const unsigned short* __restrict__ Bm,
    void* __restrict__ Cout, float* __restrict__ rowsq,
    int M, int N, int K, int nTN) {
  constexpr int NFRAG = BN / 64;   // n-fragments per wave (4 or 2)
  constexpr int NH = NFRAG / 2;    // n-fragments per quadrant (2 or 1)
  constexpr int LB = BN / 128;     // B loads per unit per thread (2 or 1)
  constexpr int ABUFE = 16384;     // elems per A tile buffer (256x64)
  constexpr int BBUFE = BN * 64;
  __shared__ unsigned short lds[2 * ABUFE + 2 * BBUFE];

  const int tid = threadIdx.x;
  const int l = tid & 63;
  const int wid = tid >> 6;
  const int wr = wid >> 2;   // 0..1
  const int wc = wid & 3;    // 0..3

  // XCD-aware bijective remap (nwg % 8 == 0 here)
  const int nwg = gridDim.x;
  const int cpx = nwg >> 3;
  const int wg = (blockIdx.x & 7) * cpx + (blockIdx.x >> 3);
  const int bx = wg % nTN;
  const int by = wg / nTN;
  const int rowBase = by * 256;
  const int colBase = bx * BN;
  const int nkt = K >> 6;

  // staging precompute: linear LDS dest, inverse-swizzled global source
  const unsigned short* aSrc[2]; int aLds[2];
#pragma unroll
  for (int j = 0; j < 2; ++j) {
    int slot = j * 512 + tid;
    int rin = slot >> 3;
    int cs = (slot & 7) ^ (rin & 7);
    aSrc[j] = A + (size_t)(rowBase + rin) * K + cs * 8;
    aLds[j] = slot * 8;
  }
  const unsigned short* bSrc[LB]; int bLds[LB];
#pragma unroll
  for (int j = 0; j < LB; ++j) {
    int slot = j * 512 + tid;
    int rin = slot >> 3;
    int cs = (slot & 7) ^ (rin & 7);
    bSrc[j] = Bm + (size_t)(colBase + rin) * K + cs * 8;
    bLds[j] = slot * 8;
  }

#define STAGE_A(u, b, kt) { _Pragma("unroll") for (int j = 0; j < 2; ++j) \
    __builtin_amdgcn_global_load_lds( \
      (const __attribute__((address_space(1))) void*)(aSrc[j] + (size_t)(u) * 128 * K + (kt) * 64), \
      (__attribute__((address_space(3))) void*)(lds + (b) * ABUFE + (u) * 8192 + aLds[j]), 16, 0, 0); }
#define STAGE_B(u, b, kt) { _Pragma("unroll") for (int j = 0; j < LB; ++j) \
    __builtin_amdgcn_global_load_lds( \
      (const __attribute__((address_space(1))) void*)(bSrc[j] + (size_t)(u) * (BN / 2) * K + (kt) * 64), \
      (__attribute__((address_space(3))) void*)(lds + 2 * ABUFE + (b) * BBUFE + (u) * (BBUFE / 2) + bLds[j]), 16, 0, 0); }

  const int kb0 = (l >> 4) * 16;  // byte offset of lane's K-chunk
  const int sw = (l & 7) << 4;    // swizzle XOR (row&7)<<4 == (l&7)<<4
  const int lr = l & 15;

  f32x4 acc[8][NFRAG];
#pragma unroll
  for (int m = 0; m < 8; ++m)
#pragma unroll
    for (int n = 0; n < NFRAG; ++n) acc[m][n] = (f32x4){0.f, 0.f, 0.f, 0.f};

  short8 a[4][2], b0[NH][2], b1[NH][2];

#define LDA(mh) { _Pragma("unroll") for (int i = 0; i < 4; ++i) { \
    int row = ((mh) * 4 + i) * 32 + wr * 16 + lr; \
    const char* pp = (const char*)lds + buf * 32768 + row * 128; \
    a[i][0] = *(const short8*)(pp + ((0 + kb0) ^ sw)); \
    a[i][1] = *(const short8*)(pp + ((64 + kb0) ^ sw)); } }
#define LDB(dst, nh) { _Pragma("unroll") for (int i = 0; i < NH; ++i) { \
    int row = ((nh) * NH + i) * 64 + wc * 16 + lr; \
    const char* pp = (const char*)lds + 2 * ABUFE * 2 + buf * BBUFE * 2 + row * 128; \
    dst[i][0] = *(const short8*)(pp + ((0 + kb0) ^ sw)); \
    dst[i][1] = *(const short8*)(pp + ((64 + kb0) ^ sw)); } }
#define DO_MFMA(mh, nh, bb) { _Pragma("unroll") for (int kk = 0; kk < 2; ++kk) \
    _Pragma("unroll") for (int i = 0; i < 4; ++i) \
    _Pragma("unroll") for (int nn = 0; nn < NH; ++nn) \
      acc[(mh) * 4 + i][(nh) * NH + nn] = __builtin_amdgcn_mfma_f32_16x16x32_bf16( \
          a[i][kk], bb[nn][kk], acc[(mh) * 4 + i][(nh) * NH + nn], 0, 0, 0); }

  // prologue: tile0 fully + tile1's A0,B0,B1 (t1.A1 staged at t0.p0)
  STAGE_A(0, 0, 0); STAGE_A(1, 0, 0); STAGE_B(0, 0, 0); STAGE_B(1, 0, 0);
  if (nkt > 1) { STAGE_A(0, 1, 1); STAGE_B(0, 1, 1); STAGE_B(1, 1, 1); }
  if constexpr (LB == 2) { VMC6; } else { VMC4; }
  BARR;

  for (int t = 0; t < nkt; ++t) {
    const int buf = t & 1;
    // phase 0: quadrant (0,0)
    LDA(0); LDB(b0, 0);
    if (t + 1 < nkt) STAGE_A(1, (t + 1) & 1, t + 1);
    BARR;
    __builtin_amdgcn_s_setprio(1); DO_MFMA(0, 0, b0); __builtin_amdgcn_s_setprio(0);
    BARR;
    // phase 1: (0,1)
    LDB(b1, 1);
    if (t + 2 < nkt) STAGE_A(0, buf, t + 2);
    BARR;
    __builtin_amdgcn_s_setprio(1); DO_MFMA(0, 1, b1); __builtin_amdgcn_s_setprio(0);
    BARR;
    // phase 2: (1,1)
    LDA(1);
    if (t + 2 < nkt) STAGE_B(0, buf, t + 2);
    BARR;
    __builtin_amdgcn_s_setprio(1); DO_MFMA(1, 1, b1); __builtin_amdgcn_s_setprio(0);
    BARR;
    // phase 3: (1,0) — reuses b0 regs from p0
    if (t + 2 < nkt) STAGE_B(1, buf, t + 2);
    BARR;
    __builtin_amdgcn_s_setprio(1); DO_MFMA(1, 0, b0); __builtin_amdgcn_s_setprio(0);
    if constexpr (LB == 2) { VMC6; } else { VMC4; }
    BARR;
  }

  // epilogue: C/D layout col=lane&15, row=(lane>>4)*4+reg
  const int cq = l >> 4;
  const int cc = l & 15;
  if constexpr (DO_SIM) {
    unsigned short* Sb = (unsigned short*)Cout;
#pragma unroll
    for (int m = 0; m < 8; ++m) {
#pragma unroll
      for (int j = 0; j < 4; ++j) {
        int gr = rowBase + m * 32 + wr * 16 + cq * 4 + j;
        float ss = 0.f;
#pragma unroll
        for (int n = 0; n < NFRAG; ++n) {
          float v = acc[m][n][j];
          ss += v * v;
          Sb[(size_t)gr * N + colBase + n * 64 + wc * 16 + cc] = f2bf(v);
        }
        ss += __shfl_xor(ss, 1, 64);
        ss += __shfl_xor(ss, 2, 64);
        ss += __shfl_xor(ss, 4, 64);
        ss += __shfl_xor(ss, 8, 64);
        if (cc == 0) atomicAdd(&rowsq[gr], ss);
      }
    }
  } else {
    float* Co = (float*)Cout;
#pragma unroll
    for (int m = 0; m < 8; ++m) {
#pragma unroll
      for (int j = 0; j < 4; ++j) {
        int gr = rowBase + m * 32 + wr * 16 + cq * 4 + j;
#pragma unroll
        for (int n = 0; n < NFRAG; ++n)
          Co[(size_t)gr * N + colBase + n * 64 + wc * 16 + cc] = acc[m][n][j];
      }
    }
  }
#undef STAGE_A
#undef STAGE_B
#undef LDA
#undef LDB
#undef DO_MFMA
}

// ---- launch ----------------------------------------------------------------

extern "C" void kernel_launch(void* const* d_in, const int* in_sizes, int n_in,
                              void* d_out, int out_size, void* d_ws, size_t ws_size,
                              hipStream_t stream) {
  (void)in_sizes; (void)n_in; (void)out_size; (void)ws_size;
  const float* x            = (const float*)d_in[0];
  const float* key_tokens   = (const float*)d_in[1];
  const float* value_tokens = (const float*)d_in[2];
  const float* key_down     = (const float*)d_in[3];
  const float* key_up       = (const float*)d_in[4];
  const float* value_down   = (const float*)d_in[5];
  const float* value_up     = (const float*)d_in[6];

  char* ws = (char*)d_ws;
  unsigned short* xb  = (unsigned short*)(ws);              // 16 MB  [8192][1024]
  unsigned short* Kb  = (unsigned short*)(ws + 16777216);   // 4 MB   [2048][1024]
  unsigned short* VbT = (unsigned short*)(ws + 20971520);   // 4 MB   [1024][2048]
  unsigned short* S   = (unsigned short*)(ws + 25165824);   // 32 MB  [8192][2048]
  float* tmpK  = (float*)(ws + 58720256);                   // 128 KB
  float* tmpV  = (float*)(ws + 58851328);                   // 128 KB
  float* rowsq = (float*)(ws + 58982400);                   // 32 KB

  hipMemsetAsync(rowsq, 0, M_TOT * sizeof(float), stream);
  down_proj_kernel<<<256, 256, 0, stream>>>(key_tokens, key_down, value_tokens, value_down, tmpK, tmpV);
  kfill_kernel<<<(N2T * IN_F) / 256, 256, 0, stream>>>(key_tokens, key_up, tmpK, Kb);
  vfill_kernel<<<512, 256, 0, stream>>>(value_tokens, value_up, tmpV, VbT);
  xcast_kernel<<<(M_TOT * IN_F) / (256 * 8), 256, 0, stream>>>(x, xb);
  // GEMM1: S = xb @ Kb^T  [8192,2048], K=1024; BN=256 -> grid 8*32=256
  gemm8p_kernel<256, 1><<<256, 512, 0, stream>>>(xb, Kb, (void*)S, rowsq, M_TOT, N2T, IN_F, N2T / 256);
  gelu_kernel<<<(M_TOT * N2T) / (256 * 8), 256, 0, stream>>>(S, rowsq);
  // GEMM2: out = W @ VbT^T [8192,1024], K=2048; BN=128 -> grid 8*32=256
  gemm8p_kernel<128, 0><<<256, 512, 0, stream>>>(S, VbT, d_out, nullptr, M_TOT, OUT_F, N2T, OUT_F / 128);
}

// Round 3
// 181.080 us; speedup vs baseline: 1.2068x; 1.0040x over previous
//
#include <hip/hip_runtime.h>

#define IN_F 1024
#define OUT_F 1024
#define NT 1024
#define RANK 32
#define M_TOT 8192   // 4*2048 query rows
#define N2T 2048     // 2*NT combined tokens

typedef __attribute__((ext_vector_type(8))) short short8;
typedef __attribute__((ext_vector_type(4))) float f32x4;
typedef __attribute__((ext_vector_type(8))) unsigned short ushort8;
typedef __attribute__((ext_vector_type(4))) unsigned short ushort4v;

__device__ __forceinline__ float geluf(float x) {
  return 0.5f * x * (1.0f + erff(x * 0.7071067811865476f));
}
__device__ __forceinline__ unsigned short f2bf(float f) {
  unsigned x = __float_as_uint(f);
  return (unsigned short)((x + 0x7fffu + ((x >> 16) & 1u)) >> 16);
}
__device__ __forceinline__ float bf2f(unsigned short u) {
  return __uint_as_float(((unsigned)u) << 16);
}

// ---- prep kernels ----------------------------------------------------------

// tmp = T @ D  ([1024][32]); one block per (mat,row), split-K across 8 chunks
__global__ void down_proj_kernel(const float* __restrict__ kt, const float* __restrict__ kd,
                                 const float* __restrict__ vt, const float* __restrict__ vd,
                                 float* __restrict__ tmpK, float* __restrict__ tmpV) {
  __shared__ float rowbuf[IN_F];
  __shared__ float part[8][32];
  const int row = blockIdx.x & (NT - 1);
  const int mat = blockIdx.x >> 10;
  const float* T = mat ? vt : kt;
  const float* D = mat ? vd : kd;
  const int tid = threadIdx.x;
  *(f32x4*)(rowbuf + tid * 4) = *(const f32x4*)(T + (size_t)row * IN_F + tid * 4);
  __syncthreads();
  const int c = tid & 31;
  const int kc = tid >> 5;  // 8 chunks of 128
  float s = 0.f;
#pragma unroll 4
  for (int k = kc * 128; k < kc * 128 + 128; ++k) s += rowbuf[k] * D[k * RANK + c];
  part[kc][c] = s;
  __syncthreads();
  if (tid < 32) {
    float acc = 0.f;
#pragma unroll
    for (int i = 0; i < 8; ++i) acc += part[i][tid];
    (mat ? tmpV : tmpK)[row * RANK + tid] = acc;
  }
}

// Kb[t][d] bf16 [2048][1024], vectorized x4
__global__ void kfill_kernel(const float* __restrict__ key_tokens, const float* __restrict__ key_up,
                             const float* __restrict__ tmpK, unsigned short* __restrict__ Kb) {
  int idx = (blockIdx.x * blockDim.x + threadIdx.x) * 4;  // 2048*1024 elems
  int d = idx & (IN_F - 1);
  int t = idx >> 10;
  ushort4v o;
  if (t < NT) {
    f32x4 v = *(const f32x4*)(key_tokens + idx);
    o[0] = f2bf(v[0]); o[1] = f2bf(v[1]); o[2] = f2bf(v[2]); o[3] = f2bf(v[3]);
  } else {
    int tt = t - NT;
    f32x4 s = {0.f, 0.f, 0.f, 0.f};
#pragma unroll
    for (int r = 0; r < RANK; ++r) {
      float u = tmpK[tt * RANK + r];
      f32x4 w = *(const f32x4*)(key_up + r * IN_F + d);
      s[0] += u * w[0]; s[1] += u * w[1]; s[2] += u * w[2]; s[3] += u * w[3];
    }
    o[0] = f2bf(geluf(s[0])); o[1] = f2bf(geluf(s[1]));
    o[2] = f2bf(geluf(s[2])); o[3] = f2bf(geluf(s[3]));
  }
  *(ushort4v*)(Kb + idx) = o;
}

// VbT[e][t] via LDS transpose
__global__ void vfill_kernel(const float* __restrict__ vt, const float* __restrict__ vu,
                             const float* __restrict__ tmpV, unsigned short* __restrict__ VbT) {
  __shared__ float tile[64][65];
  int tid = threadIdx.x;
  int bt = blockIdx.x & 31;
  int be = blockIdx.x >> 5;
  int t0 = bt * 64, e0 = be * 64;
#pragma unroll 1
  for (int it = 0; it < 16; ++it) {
    int tt = it * 4 + (tid >> 6);
    int ee = tid & 63;
    int t = t0 + tt, e = e0 + ee;
    float v;
    if (t < NT) {
      v = vt[(size_t)t * OUT_F + e];
    } else {
      int q = t - NT;
      float s = 0.f;
#pragma unroll
      for (int r = 0; r < RANK; ++r) s += tmpV[q * RANK + r] * vu[r * OUT_F + e];
      v = geluf(s);
    }
    tile[tt][ee] = v;
  }
  __syncthreads();
#pragma unroll 1
  for (int it = 0; it < 16; ++it) {
    int ee = it * 4 + (tid >> 6);
    int tt = tid & 63;
    VbT[(size_t)(e0 + ee) * N2T + t0 + tt] = f2bf(tile[tt][ee]);
  }
}

__global__ void xcast_kernel(const float* __restrict__ x, unsigned short* __restrict__ xb) {
  int base = (blockIdx.x * blockDim.x + threadIdx.x) * 8;
  f32x4 a = *(const f32x4*)(x + base);
  f32x4 b = *(const f32x4*)(x + base + 4);
  ushort8 o;
  o[0] = f2bf(a[0]); o[1] = f2bf(a[1]); o[2] = f2bf(a[2]); o[3] = f2bf(a[3]);
  o[4] = f2bf(b[0]); o[5] = f2bf(b[1]); o[6] = f2bf(b[2]); o[7] = f2bf(b[3]);
  *(ushort8*)(xb + base) = o;
}

__global__ void gelu_kernel(unsigned short* __restrict__ S, const float* __restrict__ rowsq) {
  int base = (blockIdx.x * blockDim.x + threadIdx.x) * 8;
  int row = base >> 11;
  float scale = sqrtf(2048.0f / rowsq[row]);
  ushort8 v = *(const ushort8*)(S + base);
  ushort8 o;
#pragma unroll
  for (int i = 0; i < 8; ++i) o[i] = f2bf(geluf(bf2f(v[i]) * scale));
  *(ushort8*)(S + base) = o;
}

// ---- 2-phase GEMM: C[M,N] = A[M,K]*B[N,K]^T, bf16, BM=256, BK=64, 8 waves --
// Phase A reads A0,B0,B1 (16/12 ds_read_b128) -> 32 MFMA; phase B reads A1
// (8 reads) -> 32 MFMA. Stage slots (>=1 barrier after target's last read):
//   phA: A1(t+1) -> other buf (A1 of buf^1 last read in t-1 phB)
//   phB: A0,B0,B1(t+2) -> current buf (last read in phA, barrier between)
// Boundary vmcnt(2+2*LB): drains through t.phA's A1(t+1) -> t+1 fully staged.
#define BARRB __builtin_amdgcn_s_barrier()

template <int BN, int KDIM, int NDIM, int DO_SIM>
__global__ __launch_bounds__(512, 2) void gemm2p_kernel(
    const unsigned short* __restrict__ A, const unsigned short* __restrict__ Bm,
    void* __restrict__ Cout, float* __restrict__ rowsq) {
  constexpr int NFRAG = BN / 64;
  constexpr int NH = NFRAG / 2;
  constexpr int LB = BN / 128;     // B gloads per unit per thread
  constexpr int ABUFE = 16384;     // 256x64 elems
  constexpr int BBUFE = BN * 64;
  constexpr int nTN = NDIM / BN;
  constexpr int nkt = KDIM / 64;
  __shared__ unsigned short lds[2 * ABUFE + 2 * BBUFE];

  const int tid = threadIdx.x;
  const int l = tid & 63;
  const int wid = tid >> 6;
  const int wr = wid >> 2;
  const int wc = wid & 3;

  const int nwg = gridDim.x;
  const int cpx = nwg >> 3;
  const int wg = (blockIdx.x & 7) * cpx + (blockIdx.x >> 3);
  const int bx = wg % nTN;
  const int by = wg / nTN;
  const int rowBase = by * 256;
  const int colBase = bx * BN;

  const unsigned short* aSrc[2]; int aLds[2];
#pragma unroll
  for (int j = 0; j < 2; ++j) {
    int slot = j * 512 + tid;
    int rin = slot >> 3;
    int cs = (slot & 7) ^ (rin & 7);
    aSrc[j] = A + (size_t)(rowBase + rin) * KDIM + cs * 8;
    aLds[j] = slot * 8;
  }
  const unsigned short* bSrc[LB]; int bLds[LB];
#pragma unroll
  for (int j = 0; j < LB; ++j) {
    int slot = j * 512 + tid;
    int rin = slot >> 3;
    int cs = (slot & 7) ^ (rin & 7);
    bSrc[j] = Bm + (size_t)(colBase + rin) * KDIM + cs * 8;
    bLds[j] = slot * 8;
  }

#define STAGE_A(u, b, kt) { _Pragma("unroll") for (int j = 0; j < 2; ++j) \
    __builtin_amdgcn_global_load_lds( \
      (const __attribute__((address_space(1))) void*)(aSrc[j] + (size_t)(u) * 128 * KDIM + (kt) * 64), \
      (__attribute__((address_space(3))) void*)(lds + (b) * ABUFE + (u) * 8192 + aLds[j]), 16, 0, 0); }
#define STAGE_B(u, b, kt) { _Pragma("unroll") for (int j = 0; j < LB; ++j) \
    __builtin_amdgcn_global_load_lds( \
      (const __attribute__((address_space(1))) void*)(bSrc[j] + (size_t)(u) * (BN / 2) * KDIM + (kt) * 64), \
      (__attribute__((address_space(3))) void*)(lds + 2 * ABUFE + (b) * BBUFE + (u) * (BBUFE / 2) + bLds[j]), 16, 0, 0); }

  const int kb0 = (l >> 4) * 16;
  const int sw = (l & 7) << 4;
  const int lr = l & 15;

  f32x4 acc[8][NFRAG];
#pragma unroll
  for (int m = 0; m < 8; ++m)
#pragma unroll
    for (int n = 0; n < NFRAG; ++n) acc[m][n] = (f32x4){0.f, 0.f, 0.f, 0.f};

  short8 a[4][2], b0[NH][2], b1[NH][2];

#define LDA(mh, bb_) { _Pragma("unroll") for (int i = 0; i < 4; ++i) { \
    int row = ((mh) * 4 + i) * 32 + wr * 16 + lr; \
    const char* pp = (const char*)lds + (bb_) * 32768 + row * 128; \
    a[i][0] = *(const short8*)(pp + ((0 + kb0) ^ sw)); \
    a[i][1] = *(const short8*)(pp + ((64 + kb0) ^ sw)); } }
#define LDB(dst, nh, bb_) { _Pragma("unroll") for (int i = 0; i < NH; ++i) { \
    int row = ((nh) * NH + i) * 64 + wc * 16 + lr; \
    const char* pp = (const char*)lds + 2 * ABUFE * 2 + (bb_) * BBUFE * 2 + row * 128; \
    dst[i][0] = *(const short8*)(pp + ((0 + kb0) ^ sw)); \
    dst[i][1] = *(const short8*)(pp + ((64 + kb0) ^ sw)); } }
#define DO_MFMA(mh, nh, bb) { _Pragma("unroll") for (int kk = 0; kk < 2; ++kk) \
    _Pragma("unroll") for (int i = 0; i < 4; ++i) \
    _Pragma("unroll") for (int nn = 0; nn < NH; ++nn) \
      acc[(mh) * 4 + i][(nh) * NH + nn] = __builtin_amdgcn_mfma_f32_16x16x32_bf16( \
          a[i][kk], bb[nn][kk], acc[(mh) * 4 + i][(nh) * NH + nn], 0, 0, 0); }

  // prologue: tile0 fully + tile1's A0,B0,B1 (t1.A1 staged during t0 phA)
  STAGE_A(0, 0, 0); STAGE_A(1, 0, 0); STAGE_B(0, 0, 0); STAGE_B(1, 0, 0);
  STAGE_A(0, 1, 1); STAGE_B(0, 1, 1); STAGE_B(1, 1, 1);
  if constexpr (LB == 2) { asm volatile("s_waitcnt vmcnt(6)" ::: "memory"); }
  else                   { asm volatile("s_waitcnt vmcnt(4)" ::: "memory"); }
  BARRB;

  for (int t = 0; t < nkt; ++t) {
    const int buf = t & 1;
    // ---- phase A: quadrants (0,0),(0,1) ----
    LDA(0, buf); LDB(b0, 0, buf); LDB(b1, 1, buf);
    if (t + 1 < nkt) STAGE_A(1, buf ^ 1, t + 1);
    BARRB;
    __builtin_amdgcn_s_setprio(1);
    DO_MFMA(0, 0, b0); DO_MFMA(0, 1, b1);
    __builtin_amdgcn_s_setprio(0);
    BARRB;
    // ---- phase B: quadrants (1,1),(1,0) ----
    LDA(1, buf);
    if (t + 2 < nkt) { STAGE_A(0, buf, t + 2); STAGE_B(0, buf, t + 2); STAGE_B(1, buf, t + 2); }
    BARRB;
    __builtin_amdgcn_s_setprio(1);
    DO_MFMA(1, 1, b1); DO_MFMA(1, 0, b0);
    __builtin_amdgcn_s_setprio(0);
    if constexpr (LB == 2) { asm volatile("s_waitcnt vmcnt(6)" ::: "memory"); }
    else                   { asm volatile("s_waitcnt vmcnt(4)" ::: "memory"); }
    BARRB;
  }

  // epilogue: C/D layout col=lane&15, row=(lane>>4)*4+reg
  const int cq = l >> 4;
  const int cc = l & 15;
  if constexpr (DO_SIM) {
    unsigned short* Sb = (unsigned short*)Cout;
#pragma unroll
    for (int m = 0; m < 8; ++m) {
#pragma unroll
      for (int j = 0; j < 4; ++j) {
        int gr = rowBase + m * 32 + wr * 16 + cq * 4 + j;
        float ss = 0.f;
#pragma unroll
        for (int n = 0; n < NFRAG; ++n) {
          float v = acc[m][n][j];
          ss += v * v;
          Sb[(size_t)gr * NDIM + colBase + n * 64 + wc * 16 + cc] = f2bf(v);
        }
        ss += __shfl_xor(ss, 1, 64);
        ss += __shfl_xor(ss, 2, 64);
        ss += __shfl_xor(ss, 4, 64);
        ss += __shfl_xor(ss, 8, 64);
        if (cc == 0) atomicAdd(&rowsq[gr], ss);
      }
    }
  } else {
    float* Co = (float*)Cout;
#pragma unroll
    for (int m = 0; m < 8; ++m) {
#pragma unroll
      for (int j = 0; j < 4; ++j) {
        int gr = rowBase + m * 32 + wr * 16 + cq * 4 + j;
#pragma unroll
        for (int n = 0; n < NFRAG; ++n)
          Co[(size_t)gr * NDIM + colBase + n * 64 + wc * 16 + cc] = acc[m][n][j];
      }
    }
  }
#undef STAGE_A
#undef STAGE_B
#undef LDA
#undef LDB
#undef DO_MFMA
}

// ---- launch ----------------------------------------------------------------

extern "C" void kernel_launch(void* const* d_in, const int* in_sizes, int n_in,
                              void* d_out, int out_size, void* d_ws, size_t ws_size,
                              hipStream_t stream) {
  (void)in_sizes; (void)n_in; (void)out_size; (void)ws_size;
  const float* x            = (const float*)d_in[0];
  const float* key_tokens   = (const float*)d_in[1];
  const float* value_tokens = (const float*)d_in[2];
  const float* key_down     = (const float*)d_in[3];
  const float* key_up       = (const float*)d_in[4];
  const float* value_down   = (const float*)d_in[5];
  const float* value_up     = (const float*)d_in[6];

  char* ws = (char*)d_ws;
  unsigned short* xb  = (unsigned short*)(ws);              // 16 MB  [8192][1024]
  unsigned short* Kb  = (unsigned short*)(ws + 16777216);   // 4 MB   [2048][1024]
  unsigned short* VbT = (unsigned short*)(ws + 20971520);   // 4 MB   [1024][2048]
  unsigned short* S   = (unsigned short*)(ws + 25165824);   // 32 MB  [8192][2048]
  float* tmpK  = (float*)(ws + 58720256);                   // 128 KB
  float* tmpV  = (float*)(ws + 58851328);                   // 128 KB
  float* rowsq = (float*)(ws + 58982400);                   // 32 KB

  hipMemsetAsync(rowsq, 0, M_TOT * sizeof(float), stream);
  down_proj_kernel<<<2 * NT, 256, 0, stream>>>(key_tokens, key_down, value_tokens, value_down, tmpK, tmpV);
  kfill_kernel<<<(N2T * IN_F) / (256 * 4), 256, 0, stream>>>(key_tokens, key_up, tmpK, Kb);
  vfill_kernel<<<512, 256, 0, stream>>>(value_tokens, value_up, tmpV, VbT);
  xcast_kernel<<<(M_TOT * IN_F) / (256 * 8), 256, 0, stream>>>(x, xb);
  // GEMM1: S = xb @ Kb^T  [8192,2048], K=1024; grid 32*8=256
  gemm2p_kernel<256, IN_F, N2T, 1><<<256, 512, 0, stream>>>(xb, Kb, (void*)S, rowsq);
  gelu_kernel<<<(M_TOT * N2T) / (256 * 8), 256, 0, stream>>>(S, rowsq);
  // GEMM2: out = W @ VbT^T [8192,1024], K=2048; grid 32*8=256
  gemm2p_kernel<128, N2T, OUT_F, 0><<<256, 512, 0, stream>>>(S, VbT, d_out, nullptr);
}

// Round 4
// 147.290 us; speedup vs baseline: 1.4837x; 1.2294x over previous
//
#include <hip/hip_runtime.h>

#define IN_F 1024
#define OUT_F 1024
#define NT 1024
#define RANK 32
#define M_TOT 8192   // 4*2048 query rows
#define N2T 2048     // 2*NT combined tokens

typedef __attribute__((ext_vector_type(8))) short short8;
typedef __attribute__((ext_vector_type(4))) float f32x4;
typedef __attribute__((ext_vector_type(8))) unsigned short ushort8;

__device__ __forceinline__ float geluf(float x) {
  return 0.5f * x * (1.0f + erff(x * 0.7071067811865476f));
}
__device__ __forceinline__ unsigned short f2bf(float f) {
  unsigned x = __float_as_uint(f);
  return (unsigned short)((x + 0x7fffu + ((x >> 16) & 1u)) >> 16);
}
__device__ __forceinline__ float bf2f(unsigned short u) {
  return __uint_as_float(((unsigned)u) << 16);
}

// ---- prep kernels ----------------------------------------------------------

// tmp = T @ D  ([1024][32]); one block per (mat,row), split-K across 8 chunks
__global__ void down_proj_kernel(const float* __restrict__ kt, const float* __restrict__ kd,
                                 const float* __restrict__ vt, const float* __restrict__ vd,
                                 float* __restrict__ tmpK, float* __restrict__ tmpV) {
  __shared__ float rowbuf[IN_F];
  __shared__ float part[8][32];
  const int row = blockIdx.x & (NT - 1);
  const int mat = blockIdx.x >> 10;
  const float* T = mat ? vt : kt;
  const float* D = mat ? vd : kd;
  const int tid = threadIdx.x;
  *(f32x4*)(rowbuf + tid * 4) = *(const f32x4*)(T + (size_t)row * IN_F + tid * 4);
  __syncthreads();
  const int c = tid & 31;
  const int kc = tid >> 5;  // 8 chunks of 128
  float s = 0.f;
#pragma unroll 4
  for (int k = kc * 128; k < kc * 128 + 128; ++k) s += rowbuf[k] * D[k * RANK + c];
  part[kc][c] = s;
  __syncthreads();
  if (tid < 32) {
    float acc = 0.f;
#pragma unroll
    for (int i = 0; i < 8; ++i) acc += part[i][tid];
    (mat ? tmpV : tmpK)[row * RANK + tid] = acc;
  }
}

// Kb[NT+t][d] = bf16(gelu(tmpK @ key_up)), LDS-tiled: 32 t x 64 d per block.
// lanes = d (coalesced writes); per-thread iterates 8 t.
__global__ __launch_bounds__(256) void upK_kernel(
    const float* __restrict__ tmpK, const float* __restrict__ key_up,
    unsigned short* __restrict__ Kb) {
  __shared__ float ldsT[32 * 33];   // tmp tile [32 t][32 r], pad 33
  __shared__ float ldsU[32 * 64];   // up slice [32 r][64 d]
  const int tid = threadIdx.x;
  const int t0 = (blockIdx.x >> 4) * 32;   // 32 t-tiles
  const int d0 = (blockIdx.x & 15) * 64;   // 16 d-tiles
  // stage tmp tile: 1024 floats
  {
    int row = tid >> 3, col = (tid & 7) * 4;
    f32x4 v = *(const f32x4*)(tmpK + (size_t)(t0 + row) * RANK + col);
#pragma unroll
    for (int j = 0; j < 4; ++j) ldsT[row * 33 + col + j] = v[j];
  }
  // stage up slice: 2048 floats
#pragma unroll
  for (int s = 0; s < 2; ++s) {
    int idx = s * 1024 + tid * 4;
    int r = idx >> 6, cc = idx & 63;
    *(f32x4*)(ldsU + idx) = *(const f32x4*)(key_up + (size_t)r * IN_F + d0 + cc);
  }
  __syncthreads();
  const int lane = tid & 63;
  const int w = tid >> 6;
  float acc[8];
#pragma unroll
  for (int i = 0; i < 8; ++i) acc[i] = 0.f;
#pragma unroll
  for (int r = 0; r < RANK; ++r) {
    float wv = ldsU[r * 64 + lane];
#pragma unroll
    for (int i = 0; i < 8; ++i) acc[i] += ldsT[(w * 8 + i) * 33 + r] * wv;
  }
#pragma unroll
  for (int i = 0; i < 8; ++i) {
    int t = t0 + w * 8 + i;
    Kb[(size_t)(NT + t) * IN_F + d0 + lane] = f2bf(geluf(acc[i]));
  }
}

// VbT[e][NT+t] = bf16(gelu(tmpV @ value_up)), LDS-tiled: 64 t x 32 e per block.
// lanes = t (coalesced transposed writes); per-thread iterates 8 e.
__global__ __launch_bounds__(256) void upV_kernel(
    const float* __restrict__ tmpV, const float* __restrict__ value_up,
    unsigned short* __restrict__ VbT) {
  __shared__ float ldsT[64 * 33];   // tmp tile [64 t][32 r], pad 33
  __shared__ float ldsU[32 * 32];   // up slice [32 r][32 e]
  const int tid = threadIdx.x;
  const int t0 = (blockIdx.x >> 5) * 64;   // 16 t-tiles
  const int e0 = (blockIdx.x & 31) * 32;   // 32 e-tiles
#pragma unroll
  for (int s = 0; s < 2; ++s) {
    int idx = s * 1024 + tid * 4;
    int row = idx >> 5, col = idx & 31;
    f32x4 v = *(const f32x4*)(tmpV + (size_t)(t0 + row) * RANK + col);
#pragma unroll
    for (int j = 0; j < 4; ++j) ldsT[row * 33 + col + j] = v[j];
  }
  {
    int r = tid >> 3, col = (tid & 7) * 4;
    *(f32x4*)(ldsU + r * 32 + col) = *(const f32x4*)(value_up + (size_t)r * OUT_F + e0 + col);
  }
  __syncthreads();
  const int lane = tid & 63;
  const int w = tid >> 6;
  float acc[8];
#pragma unroll
  for (int i = 0; i < 8; ++i) acc[i] = 0.f;
#pragma unroll
  for (int r = 0; r < RANK; ++r) {
    float uv = ldsT[lane * 33 + r];
#pragma unroll
    for (int i = 0; i < 8; ++i) acc[i] += uv * ldsU[r * 32 + w * 8 + i];
  }
#pragma unroll
  for (int i = 0; i < 8; ++i) {
    int e = e0 + w * 8 + i;
    VbT[(size_t)e * N2T + NT + t0 + lane] = f2bf(geluf(acc[i]));
  }
}

// VbT[e][t<NT]: pure LDS transpose of value_tokens, f32 -> bf16
__global__ void vcopy_kernel(const float* __restrict__ vt, unsigned short* __restrict__ VbT) {
  __shared__ float tile[64][65];
  int tid = threadIdx.x;
  int bt = blockIdx.x & 15;   // 1024/64 t-tiles
  int be = blockIdx.x >> 4;   // 1024/64 e-tiles
  int t0 = bt * 64, e0 = be * 64;
#pragma unroll 1
  for (int it = 0; it < 16; ++it) {
    int tt = it * 4 + (tid >> 6);
    int ee = tid & 63;
    tile[tt][ee] = vt[(size_t)(t0 + tt) * OUT_F + e0 + ee];
  }
  __syncthreads();
#pragma unroll 1
  for (int it = 0; it < 16; ++it) {
    int ee = it * 4 + (tid >> 6);
    int tt = tid & 63;
    VbT[(size_t)(e0 + ee) * N2T + t0 + tt] = f2bf(tile[tt][ee]);
  }
}

// generic f32 -> bf16 cast, x8 vectorized (used for xb and Kb first half)
__global__ void xcast_kernel(const float* __restrict__ x, unsigned short* __restrict__ xb) {
  int base = (blockIdx.x * blockDim.x + threadIdx.x) * 8;
  f32x4 a = *(const f32x4*)(x + base);
  f32x4 b = *(const f32x4*)(x + base + 4);
  ushort8 o;
  o[0] = f2bf(a[0]); o[1] = f2bf(a[1]); o[2] = f2bf(a[2]); o[3] = f2bf(a[3]);
  o[4] = f2bf(b[0]); o[5] = f2bf(b[1]); o[6] = f2bf(b[2]); o[7] = f2bf(b[3]);
  *(ushort8*)(xb + base) = o;
}

__global__ void gelu_kernel(unsigned short* __restrict__ S, const float* __restrict__ rowsq) {
  int base = (blockIdx.x * blockDim.x + threadIdx.x) * 8;
  int row = base >> 11;
  float scale = sqrtf(2048.0f / rowsq[row]);
  ushort8 v = *(const ushort8*)(S + base);
  ushort8 o;
#pragma unroll
  for (int i = 0; i < 8; ++i) o[i] = f2bf(geluf(bf2f(v[i]) * scale));
  *(ushort8*)(S + base) = o;
}

// ---- 2-phase GEMM: C[M,N] = A[M,K]*B[N,K]^T, bf16, BM=256, BK=64, 8 waves --
// Phase A reads A0,B0,B1 -> 32 MFMA; phase B reads A1 -> 32 MFMA.
// Stage slots (>=1 barrier after target region's last read):
//   phA: A1(t+1) -> other buf; phB: A0,B0,B1(t+2) -> current buf.
// Boundary vmcnt(2+2*LB): drains through t.phA's A1(t+1) -> t+1 fully staged.
#define BARRB __builtin_amdgcn_s_barrier()

template <int BN, int KDIM, int NDIM, int DO_SIM>
__global__ __launch_bounds__(512, 2) void gemm2p_kernel(
    const unsigned short* __restrict__ A, const unsigned short* __restrict__ Bm,
    void* __restrict__ Cout, float* __restrict__ rowsq) {
  constexpr int NFRAG = BN / 64;
  constexpr int NH = NFRAG / 2;
  constexpr int LB = BN / 128;     // B gloads per unit per thread
  constexpr int ABUFE = 16384;     // 256x64 elems
  constexpr int BBUFE = BN * 64;
  constexpr int nTN = NDIM / BN;
  constexpr int nkt = KDIM / 64;
  __shared__ unsigned short lds[2 * ABUFE + 2 * BBUFE];

  const int tid = threadIdx.x;
  const int l = tid & 63;
  const int wid = tid >> 6;
  const int wr = wid >> 2;
  const int wc = wid & 3;

  const int nwg = gridDim.x;
  const int cpx = nwg >> 3;
  const int wg = (blockIdx.x & 7) * cpx + (blockIdx.x >> 3);
  const int bx = wg % nTN;
  const int by = wg / nTN;
  const int rowBase = by * 256;
  const int colBase = bx * BN;

  const unsigned short* aSrc[2]; int aLds[2];
#pragma unroll
  for (int j = 0; j < 2; ++j) {
    int slot = j * 512 + tid;
    int rin = slot >> 3;
    int cs = (slot & 7) ^ (rin & 7);
    aSrc[j] = A + (size_t)(rowBase + rin) * KDIM + cs * 8;
    aLds[j] = slot * 8;
  }
  const unsigned short* bSrc[LB]; int bLds[LB];
#pragma unroll
  for (int j = 0; j < LB; ++j) {
    int slot = j * 512 + tid;
    int rin = slot >> 3;
    int cs = (slot & 7) ^ (rin & 7);
    bSrc[j] = Bm + (size_t)(colBase + rin) * KDIM + cs * 8;
    bLds[j] = slot * 8;
  }

#define STAGE_A(u, b, kt) { _Pragma("unroll") for (int j = 0; j < 2; ++j) \
    __builtin_amdgcn_global_load_lds( \
      (const __attribute__((address_space(1))) void*)(aSrc[j] + (size_t)(u) * 128 * KDIM + (kt) * 64), \
      (__attribute__((address_space(3))) void*)(lds + (b) * ABUFE + (u) * 8192 + aLds[j]), 16, 0, 0); }
#define STAGE_B(u, b, kt) { _Pragma("unroll") for (int j = 0; j < LB; ++j) \
    __builtin_amdgcn_global_load_lds( \
      (const __attribute__((address_space(1))) void*)(bSrc[j] + (size_t)(u) * (BN / 2) * KDIM + (kt) * 64), \
      (__attribute__((address_space(3))) void*)(lds + 2 * ABUFE + (b) * BBUFE + (u) * (BBUFE / 2) + bLds[j]), 16, 0, 0); }

  const int kb0 = (l >> 4) * 16;
  const int sw = (l & 7) << 4;
  const int lr = l & 15;

  f32x4 acc[8][NFRAG];
#pragma unroll
  for (int m = 0; m < 8; ++m)
#pragma unroll
    for (int n = 0; n < NFRAG; ++n) acc[m][n] = (f32x4){0.f, 0.f, 0.f, 0.f};

  short8 a[4][2], b0[NH][2], b1[NH][2];

#define LDA(mh, bb_) { _Pragma("unroll") for (int i = 0; i < 4; ++i) { \
    int row = ((mh) * 4 + i) * 32 + wr * 16 + lr; \
    const char* pp = (const char*)lds + (bb_) * 32768 + row * 128; \
    a[i][0] = *(const short8*)(pp + ((0 + kb0) ^ sw)); \
    a[i][1] = *(const short8*)(pp + ((64 + kb0) ^ sw)); } }
#define LDB(dst, nh, bb_) { _Pragma("unroll") for (int i = 0; i < NH; ++i) { \
    int row = ((nh) * NH + i) * 64 + wc * 16 + lr; \
    const char* pp = (const char*)lds + 2 * ABUFE * 2 + (bb_) * BBUFE * 2 + row * 128; \
    dst[i][0] = *(const short8*)(pp + ((0 + kb0) ^ sw)); \
    dst[i][1] = *(const short8*)(pp + ((64 + kb0) ^ sw)); } }
#define DO_MFMA(mh, nh, bb) { _Pragma("unroll") for (int kk = 0; kk < 2; ++kk) \
    _Pragma("unroll") for (int i = 0; i < 4; ++i) \
    _Pragma("unroll") for (int nn = 0; nn < NH; ++nn) \
      acc[(mh) * 4 + i][(nh) * NH + nn] = __builtin_amdgcn_mfma_f32_16x16x32_bf16( \
          a[i][kk], bb[nn][kk], acc[(mh) * 4 + i][(nh) * NH + nn], 0, 0, 0); }

  // prologue: tile0 fully + tile1's A0,B0,B1 (t1.A1 staged during t0 phA)
  STAGE_A(0, 0, 0); STAGE_A(1, 0, 0); STAGE_B(0, 0, 0); STAGE_B(1, 0, 0);
  STAGE_A(0, 1, 1); STAGE_B(0, 1, 1); STAGE_B(1, 1, 1);
  if constexpr (LB == 2) { asm volatile("s_waitcnt vmcnt(6)" ::: "memory"); }
  else                   { asm volatile("s_waitcnt vmcnt(4)" ::: "memory"); }
  BARRB;

  for (int t = 0; t < nkt; ++t) {
    const int buf = t & 1;
    // ---- phase A: quadrants (0,0),(0,1) ----
    LDA(0, buf); LDB(b0, 0, buf); LDB(b1, 1, buf);
    if (t + 1 < nkt) STAGE_A(1, buf ^ 1, t + 1);
    BARRB;
    __builtin_amdgcn_s_setprio(1);
    DO_MFMA(0, 0, b0); DO_MFMA(0, 1, b1);
    __builtin_amdgcn_s_setprio(0);
    BARRB;
    // ---- phase B: quadrants (1,1),(1,0) ----
    LDA(1, buf);
    if (t + 2 < nkt) { STAGE_A(0, buf, t + 2); STAGE_B(0, buf, t + 2); STAGE_B(1, buf, t + 2); }
    BARRB;
    __builtin_amdgcn_s_setprio(1);
    DO_MFMA(1, 1, b1); DO_MFMA(1, 0, b0);
    __builtin_amdgcn_s_setprio(0);
    if constexpr (LB == 2) { asm volatile("s_waitcnt vmcnt(6)" ::: "memory"); }
    else                   { asm volatile("s_waitcnt vmcnt(4)" ::: "memory"); }
    BARRB;
  }

  // epilogue: C/D layout col=lane&15, row=(lane>>4)*4+reg
  const int cq = l >> 4;
  const int cc = l & 15;
  if constexpr (DO_SIM) {
    unsigned short* Sb = (unsigned short*)Cout;
#pragma unroll
    for (int m = 0; m < 8; ++m) {
#pragma unroll
      for (int j = 0; j < 4; ++j) {
        int gr = rowBase + m * 32 + wr * 16 + cq * 4 + j;
        float ss = 0.f;
#pragma unroll
        for (int n = 0; n < NFRAG; ++n) {
          float v = acc[m][n][j];
          ss += v * v;
          Sb[(size_t)gr * NDIM + colBase + n * 64 + wc * 16 + cc] = f2bf(v);
        }
        ss += __shfl_xor(ss, 1, 64);
        ss += __shfl_xor(ss, 2, 64);
        ss += __shfl_xor(ss, 4, 64);
        ss += __shfl_xor(ss, 8, 64);
        if (cc == 0) atomicAdd(&rowsq[gr], ss);
      }
    }
  } else {
    float* Co = (float*)Cout;
#pragma unroll
    for (int m = 0; m < 8; ++m) {
#pragma unroll
      for (int j = 0; j < 4; ++j) {
        int gr = rowBase + m * 32 + wr * 16 + cq * 4 + j;
#pragma unroll
        for (int n = 0; n < NFRAG; ++n)
          Co[(size_t)gr * NDIM + colBase + n * 64 + wc * 16 + cc] = acc[m][n][j];
      }
    }
  }
#undef STAGE_A
#undef STAGE_B
#undef LDA
#undef LDB
#undef DO_MFMA
}

// ---- launch ----------------------------------------------------------------

extern "C" void kernel_launch(void* const* d_in, const int* in_sizes, int n_in,
                              void* d_out, int out_size, void* d_ws, size_t ws_size,
                              hipStream_t stream) {
  (void)in_sizes; (void)n_in; (void)out_size; (void)ws_size;
  const float* x            = (const float*)d_in[0];
  const float* key_tokens   = (const float*)d_in[1];
  const float* value_tokens = (const float*)d_in[2];
  const float* key_down     = (const float*)d_in[3];
  const float* key_up       = (const float*)d_in[4];
  const float* value_down   = (const float*)d_in[5];
  const float* value_up     = (const float*)d_in[6];

  char* ws = (char*)d_ws;
  unsigned short* xb  = (unsigned short*)(ws);              // 16 MB  [8192][1024]
  unsigned short* Kb  = (unsigned short*)(ws + 16777216);   // 4 MB   [2048][1024]
  unsigned short* VbT = (unsigned short*)(ws + 20971520);   // 4 MB   [1024][2048]
  unsigned short* S   = (unsigned short*)(ws + 25165824);   // 32 MB  [8192][2048]
  float* tmpK  = (float*)(ws + 58720256);                   // 128 KB
  float* tmpV  = (float*)(ws + 58851328);                   // 128 KB
  float* rowsq = (float*)(ws + 58982400);                   // 32 KB

  hipMemsetAsync(rowsq, 0, M_TOT * sizeof(float), stream);
  down_proj_kernel<<<2 * NT, 256, 0, stream>>>(key_tokens, key_down, value_tokens, value_down, tmpK, tmpV);
  // Kb first half: plain cast of key_tokens
  xcast_kernel<<<(NT * IN_F) / (256 * 8), 256, 0, stream>>>(key_tokens, Kb);
  // Kb second half: LDS-tiled up-projection
  upK_kernel<<<512, 256, 0, stream>>>(tmpK, key_up, Kb);
  // VbT first half: LDS transpose of value_tokens
  vcopy_kernel<<<256, 256, 0, stream>>>(value_tokens, VbT);
  // VbT second half: LDS-tiled up-projection with transposed coalesced writes
  upV_kernel<<<512, 256, 0, stream>>>(tmpV, value_up, VbT);
  // xb = bf16(x)
  xcast_kernel<<<(M_TOT * IN_F) / (256 * 8), 256, 0, stream>>>(x, xb);
  // GEMM1: S = xb @ Kb^T  [8192,2048], K=1024; grid 32*8=256
  gemm2p_kernel<256, IN_F, N2T, 1><<<256, 512, 0, stream>>>(xb, Kb, (void*)S, rowsq);
  gelu_kernel<<<(M_TOT * N2T) / (256 * 8), 256, 0, stream>>>(S, rowsq);
  // GEMM2: out = W @ VbT^T [8192,1024], K=2048; grid 32*8=256
  gemm2p_kernel<128, N2T, OUT_F, 0><<<256, 512, 0, stream>>>(S, VbT, d_out, nullptr);
}